// Round 5
// baseline (281.761 us; speedup 1.0000x reference)
//
#include <hip/hip_runtime.h>

// BalancedCELoss: loss = -mean( t==1 ? 2*log(p) : 1*log1p(-p) ), N = 33554432.
// 256 MB traffic -> ~41 us roofline at 6.3 TB/s.
// R1/R2 were latency-bound: compiler kept only 2 loads in flight per wave
// (VGPR=32 proves it), vmcnt(0) drain per iteration, ~104 us, 2.5 TB/s eff.
// R3: __launch_bounds__(256,4) (VGPR cap 128) + straight-line software
// pipeline (4 groups of 4 float4/int4 pairs) + sched_barrier(0) pinning the
// load clusters -> >=16 loads in flight per wave.
// (R3 and R4 benches were GPUAcquisitionTimeouts — unchanged resubmit.)

#define GRID  2048
#define BLOCK 256
#define LN2F  0.69314718055994531f

// per element: x = t ? p : 1-p ; w = 1+t ; acc += w * log2(x)   (scale ln2 later)
__device__ __forceinline__ void acc4(const float4 pv, const int4 tv, float& acc) {
  float tf0 = (float)tv.x, tf1 = (float)tv.y, tf2 = (float)tv.z, tf3 = (float)tv.w;
  float x0 = __builtin_fmaf(tf0, __builtin_fmaf(2.f, pv.x, -1.f), 1.f - pv.x);
  float x1 = __builtin_fmaf(tf1, __builtin_fmaf(2.f, pv.y, -1.f), 1.f - pv.y);
  float x2 = __builtin_fmaf(tf2, __builtin_fmaf(2.f, pv.z, -1.f), 1.f - pv.z);
  float x3 = __builtin_fmaf(tf3, __builtin_fmaf(2.f, pv.w, -1.f), 1.f - pv.w);
  float l0 = __log2f(x0), l1 = __log2f(x1), l2 = __log2f(x2), l3 = __log2f(x3);
  acc += l0; acc = __builtin_fmaf(tf0, l0, acc);
  acc += l1; acc = __builtin_fmaf(tf1, l1, acc);
  acc += l2; acc = __builtin_fmaf(tf2, l2, acc);
  acc += l3; acc = __builtin_fmaf(tf3, l3, acc);
}

__global__ __launch_bounds__(BLOCK, 4) void bce_reduce_kernel(
    const float* __restrict__ p, const int* __restrict__ t,
    float* __restrict__ partial, int n4) {
  const float4* p4 = (const float4*)p;
  const int4*   t4 = (const int4*)t;
  const int idx = blockIdx.x * BLOCK + threadIdx.x;
  const int S   = GRID * BLOCK;

  float acc = 0.f;

  if (n4 == 16 * S) {
    // fast path: exactly 16 float4 iterations per thread, 4 groups of 4,
    // software-pipelined 2 groups deep.
    float4 a0 = p4[idx + 0*S], a1 = p4[idx + 1*S], a2 = p4[idx + 2*S], a3 = p4[idx + 3*S];
    int4   u0 = t4[idx + 0*S], u1 = t4[idx + 1*S], u2 = t4[idx + 2*S], u3 = t4[idx + 3*S];
    float4 b0 = p4[idx + 4*S], b1 = p4[idx + 5*S], b2 = p4[idx + 6*S], b3 = p4[idx + 7*S];
    int4   v0 = t4[idx + 4*S], v1 = t4[idx + 5*S], v2 = t4[idx + 6*S], v3 = t4[idx + 7*S];
    __builtin_amdgcn_sched_barrier(0);   // 16 loads in flight before any compute

    acc4(a0, u0, acc); acc4(a1, u1, acc); acc4(a2, u2, acc); acc4(a3, u3, acc);
    float4 c0 = p4[idx + 8*S], c1 = p4[idx + 9*S], c2 = p4[idx + 10*S], c3 = p4[idx + 11*S];
    int4   w0 = t4[idx + 8*S], w1 = t4[idx + 9*S], w2 = t4[idx + 10*S], w3 = t4[idx + 11*S];
    __builtin_amdgcn_sched_barrier(0);

    acc4(b0, v0, acc); acc4(b1, v1, acc); acc4(b2, v2, acc); acc4(b3, v3, acc);
    float4 d0 = p4[idx + 12*S], d1 = p4[idx + 13*S], d2 = p4[idx + 14*S], d3 = p4[idx + 15*S];
    int4   z0 = t4[idx + 12*S], z1 = t4[idx + 13*S], z2 = t4[idx + 14*S], z3 = t4[idx + 15*S];
    __builtin_amdgcn_sched_barrier(0);

    acc4(c0, w0, acc); acc4(c1, w1, acc); acc4(c2, w2, acc); acc4(c3, w3, acc);
    acc4(d0, z0, acc); acc4(d1, z1, acc); acc4(d2, z2, acc); acc4(d3, z3, acc);
  } else {
    // generic fallback
    for (int i = idx; i < n4; i += S) {
      float4 pv = p4[i];
      int4   tv = t4[i];
      acc4(pv, tv, acc);
    }
  }

  // wave-64 reduce
  #pragma unroll
  for (int off = 32; off > 0; off >>= 1)
    acc += __shfl_down(acc, off, 64);

  __shared__ float s[BLOCK / 64];
  const int wave = threadIdx.x >> 6;
  if ((threadIdx.x & 63) == 0) s[wave] = acc;
  __syncthreads();

  if (threadIdx.x == 0)
    partial[blockIdx.x] = (s[0] + s[1]) + (s[2] + s[3]);
}

// Reduce GRID partials -> out = -sum * ln2 / N   (partials are in log2 units)
__global__ __launch_bounds__(256) void bce_finalize_kernel(
    const float* __restrict__ partial, float* __restrict__ out, float scale) {
  float acc = 0.f;
  for (int i = threadIdx.x; i < GRID; i += 256)
    acc += partial[i];
  #pragma unroll
  for (int off = 32; off > 0; off >>= 1)
    acc += __shfl_down(acc, off, 64);
  __shared__ float s[4];
  const int wave = threadIdx.x >> 6;
  if ((threadIdx.x & 63) == 0) s[wave] = acc;
  __syncthreads();
  if (threadIdx.x == 0)
    out[0] = ((s[0] + s[1]) + (s[2] + s[3])) * scale;
}

extern "C" void kernel_launch(void* const* d_in, const int* in_sizes, int n_in,
                              void* d_out, int out_size, void* d_ws, size_t ws_size,
                              hipStream_t stream) {
  const float* p = (const float*)d_in[0];
  const int*   t = (const int*)d_in[1];
  float* out = (float*)d_out;
  float* ws  = (float*)d_ws;  // GRID floats of per-block partials (all overwritten)

  const int n  = in_sizes[0];
  const int n4 = n / 4;

  bce_reduce_kernel<<<GRID, BLOCK, 0, stream>>>(p, t, ws, n4);
  bce_finalize_kernel<<<1, 256, 0, stream>>>(ws, out, -LN2F / (float)n);
}

// Round 7
// 273.515 us; speedup vs baseline: 1.0301x; 1.0301x over previous
//
#include <hip/hip_runtime.h>

// BalancedCELoss: loss = -mean( t==1 ? 2*log(p) : 1*log1p(-p) ), N = 33554432.
// 256 MB traffic. R1/R2/R5 all ~104-118 us: latency*MLP-bound (compiler keeps
// only ~2-4 loads in flight per wave; 1.0-1.3 TB/s HBM matches the
// waves/CU x loads x 32B / 375ns latency model).
// R7: FORCE 16-18 loads in flight per wave via inline-asm global_load_dwordx4
// (volatile => program order) + hand-counted s_waitcnt vmcnt(N) ("memory"
// clobber) + sched_barrier(0) fence after each wait (guide rule #18 — tied
// "+v" vector operands don't compile, R6).

#define GRID  2048
#define BLOCK 256
#define ITERS 16
#define LN2F  0.69314718055994531f

// per element: x = t ? p : 1-p ; w = 1+t ; acc += w * log2(x)  (scale by -ln2/N later)
__device__ __forceinline__ void acc4(const float4 pv, const int4 tv, float& acc) {
  float tf0 = (float)tv.x, tf1 = (float)tv.y, tf2 = (float)tv.z, tf3 = (float)tv.w;
  float x0 = __builtin_fmaf(tf0, __builtin_fmaf(2.f, pv.x, -1.f), 1.f - pv.x);
  float x1 = __builtin_fmaf(tf1, __builtin_fmaf(2.f, pv.y, -1.f), 1.f - pv.y);
  float x2 = __builtin_fmaf(tf2, __builtin_fmaf(2.f, pv.z, -1.f), 1.f - pv.z);
  float x3 = __builtin_fmaf(tf3, __builtin_fmaf(2.f, pv.w, -1.f), 1.f - pv.w);
  float l0 = __log2f(x0), l1 = __log2f(x1), l2 = __log2f(x2), l3 = __log2f(x3);
  acc += l0; acc = __builtin_fmaf(tf0, l0, acc);
  acc += l1; acc = __builtin_fmaf(tf1, l1, acc);
  acc += l2; acc = __builtin_fmaf(tf2, l2, acc);
  acc += l3; acc = __builtin_fmaf(tf3, l3, acc);
}

__global__ __launch_bounds__(BLOCK, 4) void bce_reduce_kernel(
    const float* __restrict__ p, const int* __restrict__ t,
    float* __restrict__ partial, int n4) {
  const float4* p4 = (const float4*)p;
  const int4*   t4 = (const int4*)t;
  const int idx = blockIdx.x * BLOCK + threadIdx.x;
  const int S   = GRID * BLOCK;  // float4 stride per iteration

  float acc = 0.f;

  if (n4 == ITERS * S) {
    const float4* pb = p4 + idx;
    const int4*   tb = t4 + idx;

    float4 pv0, pv1, pv2, pv3, pv4, pv5, pv6, pv7,
           pv8, pv9, pv10, pv11, pv12, pv13, pv14, pv15;
    int4   tv0, tv1, tv2, tv3, tv4, tv5, tv6, tv7,
           tv8, tv9, tv10, tv11, tv12, tv13, tv14, tv15;

    // issue pair k (p then t); volatile asm preserves program order
    #define ISSUE(k) \
      asm volatile("global_load_dwordx4 %0, %1, off" : "=v"(pv##k) : "v"(pb + (k) * S)); \
      asm volatile("global_load_dwordx4 %0, %1, off" : "=v"(tv##k) : "v"(tb + (k) * S));
    // wait until <= n VMEM ops outstanding; sched_barrier(0) stops the
    // scheduler hoisting the (register-only) consumer above the wait (rule #18)
    #define WAITC(n) \
      asm volatile("s_waitcnt vmcnt(" #n ")" ::: "memory"); \
      __builtin_amdgcn_sched_barrier(0);

    // prologue: 8 pairs = 16 loads in flight
    ISSUE(0) ISSUE(1) ISSUE(2) ISSUE(3) ISSUE(4) ISSUE(5) ISSUE(6) ISSUE(7)

    // steady state: issue pair k+8 (-> 18 outstanding), wait to 16 (pair k
    // complete), consume pair k.
    ISSUE(8)  WAITC(16) acc4(pv0, tv0, acc);
    ISSUE(9)  WAITC(16) acc4(pv1, tv1, acc);
    ISSUE(10) WAITC(16) acc4(pv2, tv2, acc);
    ISSUE(11) WAITC(16) acc4(pv3, tv3, acc);
    ISSUE(12) WAITC(16) acc4(pv4, tv4, acc);
    ISSUE(13) WAITC(16) acc4(pv5, tv5, acc);
    ISSUE(14) WAITC(16) acc4(pv6, tv6, acc);
    ISSUE(15) WAITC(16) acc4(pv7, tv7, acc);
    // drain: pairs 8..15 outstanding (16 ops), oldest-first
    WAITC(14) acc4(pv8,  tv8,  acc);
    WAITC(12) acc4(pv9,  tv9,  acc);
    WAITC(10) acc4(pv10, tv10, acc);
    WAITC(8)  acc4(pv11, tv11, acc);
    WAITC(6)  acc4(pv12, tv12, acc);
    WAITC(4)  acc4(pv13, tv13, acc);
    WAITC(2)  acc4(pv14, tv14, acc);
    WAITC(0)  acc4(pv15, tv15, acc);

    #undef ISSUE
    #undef WAITC
  } else {
    // generic fallback
    for (int i = idx; i < n4; i += S) {
      float4 pv = p4[i];
      int4   tv = t4[i];
      acc4(pv, tv, acc);
    }
  }

  // wave-64 reduce
  #pragma unroll
  for (int off = 32; off > 0; off >>= 1)
    acc += __shfl_down(acc, off, 64);

  __shared__ float s[BLOCK / 64];
  const int wave = threadIdx.x >> 6;
  if ((threadIdx.x & 63) == 0) s[wave] = acc;
  __syncthreads();

  if (threadIdx.x == 0)
    partial[blockIdx.x] = (s[0] + s[1]) + (s[2] + s[3]);
}

// Reduce GRID partials -> out = -sum * ln2 / N   (partials are in log2 units)
__global__ __launch_bounds__(256) void bce_finalize_kernel(
    const float* __restrict__ partial, float* __restrict__ out, float scale) {
  float acc = 0.f;
  for (int i = threadIdx.x; i < GRID; i += 256)
    acc += partial[i];
  #pragma unroll
  for (int off = 32; off > 0; off >>= 1)
    acc += __shfl_down(acc, off, 64);
  __shared__ float s[4];
  const int wave = threadIdx.x >> 6;
  if ((threadIdx.x & 63) == 0) s[wave] = acc;
  __syncthreads();
  if (threadIdx.x == 0)
    out[0] = ((s[0] + s[1]) + (s[2] + s[3])) * scale;
}

extern "C" void kernel_launch(void* const* d_in, const int* in_sizes, int n_in,
                              void* d_out, int out_size, void* d_ws, size_t ws_size,
                              hipStream_t stream) {
  const float* p = (const float*)d_in[0];
  const int*   t = (const int*)d_in[1];
  float* out = (float*)d_out;
  float* ws  = (float*)d_ws;  // GRID floats of per-block partials (all overwritten)

  const int n  = in_sizes[0];
  const int n4 = n / 4;

  bce_reduce_kernel<<<GRID, BLOCK, 0, stream>>>(p, t, ws, n4);
  bce_finalize_kernel<<<1, 256, 0, stream>>>(ws, out, -LN2F / (float)n);
}